// Round 1
// baseline (630.336 us; speedup 1.0000x reference)
//
#include <hip/hip_runtime.h>
#include <hip/hip_bf16.h>

#define D_MODEL 1024
#define NHEAD   16
#define HD      64
#define NB      4
#define SQ      1024
#define SK      2048

typedef __attribute__((ext_vector_type(8))) short bh8;
typedef __attribute__((ext_vector_type(4))) float fx4;

__device__ __forceinline__ unsigned short f2bf(float f) {
  union { float f; unsigned u; } v; v.f = f;
  return (unsigned short)((v.u + 0x7FFFu + ((v.u >> 16) & 1u)) >> 16);
}

__device__ __forceinline__ bh8 cvt8(const float* __restrict__ p) {
  const float4 a = *(const float4*)p;
  const float4 b = *(const float4*)(p + 4);
  bh8 r;
  r[0] = (short)f2bf(a.x); r[1] = (short)f2bf(a.y);
  r[2] = (short)f2bf(a.z); r[3] = (short)f2bf(a.w);
  r[4] = (short)f2bf(b.x); r[5] = (short)f2bf(b.y);
  r[6] = (short)f2bf(b.z); r[7] = (short)f2bf(b.w);
  return r;
}

__device__ __forceinline__ bh8 ld8(const unsigned short* p) {
  return *(const bh8*)p;
}

// MODE 0: Q proj (+RoPE stride 2, L=1024, out [B][H][S][D])
// MODE 1: K proj (+RoPE stride 1, L=2048, out [B][H][K][D])
// MODE 2: V proj (no RoPE, out transposed [B][H][D][K])
template <int MODE>
__global__ __launch_bounds__(256, 2) void proj_kernel(
    const float* __restrict__ X, const float* __restrict__ W,
    const float* __restrict__ bias, unsigned short* __restrict__ out)
{
  constexpr int L = (MODE == 0) ? SQ : SK;
  constexpr int LSH = (MODE == 0) ? 10 : 11;
  const int lane = threadIdx.x & 63;
  const int wave = threadIdx.x >> 6;
  const int row0 = blockIdx.y * 128 + (wave >> 1) * 64;
  const int col0 = blockIdx.x * 128 + (wave & 1) * 64;
  const int lr = lane & 15;
  const int kl = (lane >> 4) * 8;

  fx4 acc[4][4] = {};
  for (int k0 = 0; k0 < D_MODEL; k0 += 32) {
    bh8 af[4], bf[4];
#pragma unroll
    for (int mi = 0; mi < 4; ++mi)
      af[mi] = cvt8(X + (size_t)(row0 + mi * 16 + lr) * D_MODEL + k0 + kl);
#pragma unroll
    for (int ni = 0; ni < 4; ++ni)
      bf[ni] = cvt8(W + (size_t)(col0 + ni * 16 + lr) * D_MODEL + k0 + kl);
#pragma unroll
    for (int mi = 0; mi < 4; ++mi)
#pragma unroll
      for (int ni = 0; ni < 4; ++ni)
        acc[mi][ni] = __builtin_amdgcn_mfma_f32_16x16x32_bf16(af[mi], bf[ni], acc[mi][ni], 0, 0, 0);
  }

  float bv[4];
#pragma unroll
  for (int ni = 0; ni < 4; ++ni) bv[ni] = bias[col0 + ni * 16 + lr];
#pragma unroll
  for (int mi = 0; mi < 4; ++mi)
#pragma unroll
    for (int ni = 0; ni < 4; ++ni)
#pragma unroll
      for (int j = 0; j < 4; ++j) acc[mi][ni][j] += bv[ni];

  if (MODE <= 1) {
    // inv_freq[d] = 10000^(-d/32) = 2^(-d*log2(10000)/32), d = 0..31
    const float c0 = 0.41524101186092029f;  // log2(10000)/32
    const float invf0 = exp2f(-(float)lr * c0);
    const float invf1 = exp2f(-(float)(16 + lr) * c0);
#pragma unroll
    for (int mi = 0; mi < 4; ++mi) {
#pragma unroll
      for (int j = 0; j < 4; ++j) {
        const int rg = row0 + mi * 16 + ((lane >> 4) << 2) + j;
        const int s = rg & (L - 1);
        const float pos = (float)(MODE == 0 ? 2 * s : s);
#pragma unroll
        for (int ni = 0; ni < 2; ++ni) {
          float sn, cs;
          __sincosf(pos * (ni == 0 ? invf0 : invf1), &sn, &cs);
          const float x1 = acc[mi][ni][j], x2 = acc[mi][ni + 2][j];
          acc[mi][ni][j]     = x1 * cs - x2 * sn;
          acc[mi][ni + 2][j] = x2 * cs + x1 * sn;
        }
      }
    }
  }

  const int h = (col0 >> 6);  // 64-col tile spans exactly one head
#pragma unroll
  for (int mi = 0; mi < 4; ++mi)
#pragma unroll
    for (int j = 0; j < 4; ++j) {
      const int rg = row0 + mi * 16 + ((lane >> 4) << 2) + j;
      const int bb = rg >> LSH;
      const int s = rg & (L - 1);
#pragma unroll
      for (int ni = 0; ni < 4; ++ni) {
        const int d = ni * 16 + lr;
        size_t addr;
        if (MODE == 2)
          addr = (((size_t)(bb * NHEAD + h)) * HD + d) * SK + s;
        else
          addr = (((size_t)(bb * NHEAD + h)) * L + s) * HD + d;
        out[addr] = f2bf(acc[mi][ni][j]);
      }
    }
}

// attn: one wave = 32 q rows; block = 4 waves = 128 q rows of one (b,h)
__global__ __launch_bounds__(256, 2) void attn_kernel(
    const unsigned short* __restrict__ Qr,
    const unsigned short* __restrict__ Kr,
    const unsigned short* __restrict__ Vt,
    unsigned short* __restrict__ O)
{
  __shared__ __align__(16) unsigned short p_lds[4][32][72];
  const int lane = threadIdx.x & 63;
  const int wave = threadIdx.x >> 6;
  const int bh = blockIdx.x;
  const int b = bh >> 4;
  const int h = bh & 15;
  const int q0 = blockIdx.y * 128 + wave * 32;
  const int lr = lane & 15;
  const int kl = (lane >> 4) * 8;

  const unsigned short* Qp = Qr + (size_t)bh * SQ * HD;
  const unsigned short* Kp = Kr + (size_t)bh * SK * HD;
  const unsigned short* Vp = Vt + (size_t)bh * HD * SK;

  bh8 qf[2][2];
#pragma unroll
  for (int mi = 0; mi < 2; ++mi)
#pragma unroll
    for (int kk = 0; kk < 2; ++kk)
      qf[mi][kk] = ld8(Qp + (size_t)(q0 + mi * 16 + lr) * HD + kk * 32 + kl);

  fx4 oacc[2][4] = {};
  float m[2][4], l[2][4];
#pragma unroll
  for (int mi = 0; mi < 2; ++mi)
#pragma unroll
    for (int j = 0; j < 4; ++j) { m[mi][j] = -1e30f; l[mi][j] = 0.f; }

  for (int t = 0; t < SK / 64; ++t) {
    const int kb = t * 64;
    fx4 sacc[2][4] = {};
#pragma unroll
    for (int kk = 0; kk < 2; ++kk) {
      bh8 kf[4];
#pragma unroll
      for (int ni = 0; ni < 4; ++ni)
        kf[ni] = ld8(Kp + (size_t)(kb + ni * 16 + lr) * HD + kk * 32 + kl);
#pragma unroll
      for (int mi = 0; mi < 2; ++mi)
#pragma unroll
        for (int ni = 0; ni < 4; ++ni)
          sacc[mi][ni] = __builtin_amdgcn_mfma_f32_16x16x32_bf16(qf[mi][kk], kf[ni], sacc[mi][ni], 0, 0, 0);
    }

#pragma unroll
    for (int mi = 0; mi < 2; ++mi)
#pragma unroll
      for (int j = 0; j < 4; ++j) {
        float s0 = sacc[mi][0][j] * 0.125f;
        float s1 = sacc[mi][1][j] * 0.125f;
        float s2 = sacc[mi][2][j] * 0.125f;
        float s3 = sacc[mi][3][j] * 0.125f;
        float rmax = fmaxf(fmaxf(s0, s1), fmaxf(s2, s3));
        rmax = fmaxf(rmax, __shfl_xor(rmax, 1));
        rmax = fmaxf(rmax, __shfl_xor(rmax, 2));
        rmax = fmaxf(rmax, __shfl_xor(rmax, 4));
        rmax = fmaxf(rmax, __shfl_xor(rmax, 8));
        const float mnew = fmaxf(m[mi][j], rmax);
        const float alpha = __expf(m[mi][j] - mnew);
        m[mi][j] = mnew;
        const float p0 = __expf(s0 - mnew);
        const float p1 = __expf(s1 - mnew);
        const float p2 = __expf(s2 - mnew);
        const float p3 = __expf(s3 - mnew);
        sacc[mi][0][j] = p0; sacc[mi][1][j] = p1;
        sacc[mi][2][j] = p2; sacc[mi][3][j] = p3;
        float rsum = p0 + p1 + p2 + p3;
        rsum += __shfl_xor(rsum, 1);
        rsum += __shfl_xor(rsum, 2);
        rsum += __shfl_xor(rsum, 4);
        rsum += __shfl_xor(rsum, 8);
        l[mi][j] = l[mi][j] * alpha + rsum;
#pragma unroll
        for (int ni = 0; ni < 4; ++ni) oacc[mi][ni][j] *= alpha;
      }

#pragma unroll
    for (int mi = 0; mi < 2; ++mi)
#pragma unroll
      for (int ni = 0; ni < 4; ++ni)
#pragma unroll
        for (int j = 0; j < 4; ++j)
          p_lds[wave][mi * 16 + ((lane >> 4) << 2) + j][ni * 16 + lr] = f2bf(sacc[mi][ni][j]);

    __syncthreads();

#pragma unroll
    for (int kk = 0; kk < 2; ++kk) {
      bh8 pa[2], vb[4];
#pragma unroll
      for (int mi = 0; mi < 2; ++mi)
        pa[mi] = ld8(&p_lds[wave][mi * 16 + lr][kk * 32 + kl]);
#pragma unroll
      for (int ni = 0; ni < 4; ++ni)
        vb[ni] = ld8(Vp + (size_t)(ni * 16 + lr) * SK + kb + kk * 32 + kl);
#pragma unroll
      for (int mi = 0; mi < 2; ++mi)
#pragma unroll
        for (int ni = 0; ni < 4; ++ni)
          oacc[mi][ni] = __builtin_amdgcn_mfma_f32_16x16x32_bf16(pa[mi], vb[ni], oacc[mi][ni], 0, 0, 0);
    }
    __syncthreads();
  }

#pragma unroll
  for (int mi = 0; mi < 2; ++mi)
#pragma unroll
    for (int j = 0; j < 4; ++j) {
      const float inv = 1.f / l[mi][j];
      const int s = q0 + mi * 16 + ((lane >> 4) << 2) + j;
#pragma unroll
      for (int ni = 0; ni < 4; ++ni) {
        const int d = ni * 16 + lr;
        O[((size_t)b * SQ + s) * D_MODEL + h * HD + d] = f2bf(oacc[mi][ni][j] * inv);
      }
    }
}

__global__ __launch_bounds__(256, 2) void outproj_kernel(
    const unsigned short* __restrict__ A, const float* __restrict__ W,
    const float* __restrict__ bias, float* __restrict__ out)
{
  const int lane = threadIdx.x & 63;
  const int wave = threadIdx.x >> 6;
  const int row0 = blockIdx.y * 128 + (wave >> 1) * 64;
  const int col0 = blockIdx.x * 128 + (wave & 1) * 64;
  const int lr = lane & 15;
  const int kl = (lane >> 4) * 8;

  fx4 acc[4][4] = {};
  for (int k0 = 0; k0 < D_MODEL; k0 += 32) {
    bh8 af[4], bf[4];
#pragma unroll
    for (int mi = 0; mi < 4; ++mi)
      af[mi] = ld8(A + (size_t)(row0 + mi * 16 + lr) * D_MODEL + k0 + kl);
#pragma unroll
    for (int ni = 0; ni < 4; ++ni)
      bf[ni] = cvt8(W + (size_t)(col0 + ni * 16 + lr) * D_MODEL + k0 + kl);
#pragma unroll
    for (int mi = 0; mi < 4; ++mi)
#pragma unroll
      for (int ni = 0; ni < 4; ++ni)
        acc[mi][ni] = __builtin_amdgcn_mfma_f32_16x16x32_bf16(af[mi], bf[ni], acc[mi][ni], 0, 0, 0);
  }

  float bv[4];
#pragma unroll
  for (int ni = 0; ni < 4; ++ni) bv[ni] = bias[col0 + ni * 16 + lr];

#pragma unroll
  for (int mi = 0; mi < 4; ++mi)
#pragma unroll
    for (int j = 0; j < 4; ++j) {
      const int rg = row0 + mi * 16 + ((lane >> 4) << 2) + j;
#pragma unroll
      for (int ni = 0; ni < 4; ++ni)
        out[(size_t)rg * D_MODEL + col0 + ni * 16 + lr] = acc[mi][ni][j] + bv[ni];
    }
}

extern "C" void kernel_launch(void* const* d_in, const int* in_sizes, int n_in,
                              void* d_out, int out_size, void* d_ws, size_t ws_size,
                              hipStream_t stream) {
  (void)in_sizes; (void)n_in; (void)out_size; (void)ws_size;
  const float* query = (const float*)d_in[0];
  const float* kv    = (const float*)d_in[1];
  const float* q_w   = (const float*)d_in[2];
  const float* q_b   = (const float*)d_in[3];
  const float* k_w   = (const float*)d_in[4];
  const float* k_b   = (const float*)d_in[5];
  const float* v_w   = (const float*)d_in[6];
  const float* v_b   = (const float*)d_in[7];
  const float* out_w = (const float*)d_in[8];
  const float* out_b = (const float*)d_in[9];
  float* out = (float*)d_out;

  unsigned short* ws = (unsigned short*)d_ws;
  unsigned short* q_rope = ws;                      // [B][H][S][D]   4Mi elems
  unsigned short* k_rope = ws + ((size_t)4 << 20);  // [B][H][K][D]   8Mi
  unsigned short* v_t    = ws + ((size_t)12 << 20); // [B][H][D][K]   8Mi
  unsigned short* attn_o = ws + ((size_t)20 << 20); // [B][S][HD*NH]  4Mi

  dim3 blk(256);
  hipLaunchKernelGGL((proj_kernel<0>), dim3(8, 32), blk, 0, stream, query, q_w, q_b, q_rope);
  hipLaunchKernelGGL((proj_kernel<1>), dim3(8, 64), blk, 0, stream, kv, k_w, k_b, k_rope);
  hipLaunchKernelGGL((proj_kernel<2>), dim3(8, 64), blk, 0, stream, kv, v_w, v_b, v_t);
  hipLaunchKernelGGL(attn_kernel, dim3(64, 8), blk, 0, stream, q_rope, k_rope, v_t, attn_o);
  hipLaunchKernelGGL(outproj_kernel, dim3(8, 32), blk, 0, stream, attn_o, out_w, out_b, out);
}

// Round 2
// 233.732 us; speedup vs baseline: 2.6968x; 2.6968x over previous
//
#include <hip/hip_runtime.h>
#include <hip/hip_bf16.h>

#define D_MODEL 1024
#define NHEAD   16
#define HD      64
#define SQ      1024
#define SK      2048

typedef __attribute__((ext_vector_type(8))) short bh8;
typedef __attribute__((ext_vector_type(4))) float fx4;

// scale fold: 1/sqrt(64) * log2(e)
#define QSCALE 0.1803368801111204f

__device__ __forceinline__ unsigned short f2bf(float f) {
  union { float f; unsigned u; } v; v.f = f;
  return (unsigned short)((v.u + 0x7FFFu + ((v.u >> 16) & 1u)) >> 16);
}

#define GLOAD_LDS16(gp, lp)                                                  \
  __builtin_amdgcn_global_load_lds(                                         \
      (const __attribute__((address_space(1))) unsigned int*)(gp),          \
      (__attribute__((address_space(3))) unsigned int*)(lp), 16, 0, 0)

// ---------------- f32 -> bf16 conversion pass ----------------
__global__ __launch_bounds__(256) void cvt_kernel(
    const float* __restrict__ q, const float* __restrict__ kv,
    const float* __restrict__ qw, const float* __restrict__ kw,
    const float* __restrict__ vw, const float* __restrict__ ow,
    unsigned short* __restrict__ qx, unsigned short* __restrict__ kvx,
    unsigned short* __restrict__ qwx, unsigned short* __restrict__ kwx,
    unsigned short* __restrict__ vwx, unsigned short* __restrict__ owx)
{
  const int idx = blockIdx.x * 256 + threadIdx.x;  // vec8 unit, total 2097152
  const float* src; unsigned short* dst; size_t off;
  if (idx < 524288)        { src = q;  dst = qx;  off = idx; }
  else if (idx < 1572864)  { src = kv; dst = kvx; off = idx - 524288; }
  else {
    const int w = idx - 1572864; const int sel = w >> 17; off = w & 131071;
    src = sel == 0 ? qw : sel == 1 ? kw : sel == 2 ? vw : ow;
    dst = sel == 0 ? qwx : sel == 1 ? kwx : sel == 2 ? vwx : owx;
  }
  const float4 a = ((const float4*)src)[off * 2];
  const float4 b = ((const float4*)src)[off * 2 + 1];
  bh8 r;
  r[0] = (short)f2bf(a.x); r[1] = (short)f2bf(a.y);
  r[2] = (short)f2bf(a.z); r[3] = (short)f2bf(a.w);
  r[4] = (short)f2bf(b.x); r[5] = (short)f2bf(b.y);
  r[6] = (short)f2bf(b.z); r[7] = (short)f2bf(b.w);
  *(bh8*)(dst + off * 8) = r;
}

// ---------------- projection GEMMs (m97-style, bf16, LDS-staged) ----------
// MODE 0: Q proj   (MI=2, BM=64,  L=1024, RoPE pos=2s, *QSCALE, out [bh][s][d])
// MODE 1: K+V fused(MI=4, BM=128, L=2048, cols<1024: K (RoPE pos=s, K-tiled),
//                   cols>=1024: V (V-tiled))
// MODE 2: out proj (MI=2, BM=64, f32 output + bias)
template <int MODE, int MI>
__global__ __launch_bounds__(256) void proj_kernel(
    const unsigned short* __restrict__ X,
    const unsigned short* __restrict__ W0, const unsigned short* __restrict__ W1,
    const float* __restrict__ b0, const float* __restrict__ b1,
    unsigned short* __restrict__ out0, unsigned short* __restrict__ out1,
    float* __restrict__ outf)
{
  constexpr int BM = MI * 32;
  constexpr int LSH = (MODE == 1) ? 11 : 10;
  __shared__ unsigned short Alds[BM * 32];
  __shared__ unsigned short Blds[128 * 32];

  const int t = threadIdx.x;
  const int lane = t & 63, w = t >> 6;
  const int lr = lane & 15, g = lane >> 4, kl = g * 8;
  const int row0 = blockIdx.y * BM;
  const int colB = blockIdx.x * 128;
  const int wrow = (w >> 1) * (MI * 16);
  const int wcol = (w & 1) * 64;

  const unsigned short* Wsrc = W0;
  const float* bias = b0;
  unsigned short* outp = out0;
  int colW = colB;
  bool isV = false;
  if (MODE == 1 && colB >= 1024) {
    Wsrc = W1; bias = b1; outp = out1; colW = colB - 1024; isV = true;
  }

  const int srow = t >> 2, schunk = (t & 3) * 8;

  fx4 acc[MI][4] = {};
  for (int k0 = 0; k0 < 1024; k0 += 32) {
    __syncthreads();
    GLOAD_LDS16(X + (size_t)(row0 + srow) * 1024 + k0 + schunk, &Alds[t * 8]);
    if (MI == 4)
      GLOAD_LDS16(X + (size_t)(row0 + 64 + srow) * 1024 + k0 + schunk, &Alds[2048 + t * 8]);
    GLOAD_LDS16(Wsrc + (size_t)(colW + srow) * 1024 + k0 + schunk, &Blds[t * 8]);
    GLOAD_LDS16(Wsrc + (size_t)(colW + 64 + srow) * 1024 + k0 + schunk, &Blds[2048 + t * 8]);
    __syncthreads();  // compiler drains vmcnt(0) here

    bh8 af[MI], bf[4];
#pragma unroll
    for (int mi = 0; mi < MI; ++mi)
      af[mi] = *(const bh8*)&Alds[(wrow + mi * 16 + lr) * 32 + kl];
#pragma unroll
    for (int ni = 0; ni < 4; ++ni)
      bf[ni] = *(const bh8*)&Blds[(wcol + ni * 16 + lr) * 32 + kl];
#pragma unroll
    for (int mi = 0; mi < MI; ++mi)
#pragma unroll
      for (int ni = 0; ni < 4; ++ni)
        acc[mi][ni] = __builtin_amdgcn_mfma_f32_16x16x32_bf16(af[mi], bf[ni], acc[mi][ni], 0, 0, 0);
  }

  float bv[4];
#pragma unroll
  for (int ni = 0; ni < 4; ++ni) bv[ni] = bias[colW + wcol + ni * 16 + lr];
#pragma unroll
  for (int mi = 0; mi < MI; ++mi)
#pragma unroll
    for (int ni = 0; ni < 4; ++ni)
#pragma unroll
      for (int j = 0; j < 4; ++j) acc[mi][ni][j] += bv[ni];

  if (MODE == 0 || (MODE == 1 && !isV)) {
    const float c0 = 0.41524101186092029f;  // log2(10000)/32
    const float invf0 = exp2f(-(float)lr * c0);
    const float invf1 = exp2f(-(float)(16 + lr) * c0);
#pragma unroll
    for (int mi = 0; mi < MI; ++mi)
#pragma unroll
      for (int j = 0; j < 4; ++j) {
        const int rg = row0 + wrow + mi * 16 + 4 * g + j;
        const int s = rg & ((MODE == 0) ? 1023 : 2047);
        const float pos = (float)((MODE == 0) ? 2 * s : s);
#pragma unroll
        for (int ni = 0; ni < 2; ++ni) {
          float sn, cs;
          __sincosf(pos * (ni == 0 ? invf0 : invf1), &sn, &cs);
          const float x1 = acc[mi][ni][j], x2 = acc[mi][ni + 2][j];
          acc[mi][ni][j]     = x1 * cs - x2 * sn;
          acc[mi][ni + 2][j] = x2 * cs + x1 * sn;
        }
      }
  }

  const int h = (colW + wcol) >> 6;
#pragma unroll
  for (int mi = 0; mi < MI; ++mi)
#pragma unroll
    for (int j = 0; j < 4; ++j) {
      const int rg = row0 + wrow + mi * 16 + 4 * g + j;
      const int bb = rg >> LSH;
      const int s = rg & ((1 << LSH) - 1);
#pragma unroll
      for (int ni = 0; ni < 4; ++ni) {
        const int d = ni * 16 + lr;
        if (MODE == 0) {
          outp[(((size_t)(bb * 16 + h)) * SQ + s) * 64 + d] = f2bf(acc[mi][ni][j] * QSCALE);
        } else if (MODE == 1) {
          const size_t base = ((size_t)(bb * 16 + h)) * (SK * 64);
          if (!isV) {
            outp[base + (s >> 4) * 1024 + (d >> 5) * 512 + ((d >> 3) & 3) * 128 + (s & 15) * 8 + (d & 7)]
                = f2bf(acc[mi][ni][j]);
          } else {
            outp[base + (s >> 5) * 2048 + (d >> 4) * 512 + ((s >> 3) & 3) * 128 + (d & 15) * 8 + (s & 7)]
                = f2bf(acc[mi][ni][j]);
          }
        } else {
          outf[(size_t)rg * 1024 + colB + wcol + ni * 16 + lr] = acc[mi][ni][j];
        }
      }
    }
}

// ---------------- flash attention: 1 wave per block, 32 q rows ------------
__global__ __launch_bounds__(64) void attn_kernel(
    const unsigned short* __restrict__ Qr, const unsigned short* __restrict__ Kt,
    const unsigned short* __restrict__ Vt, unsigned short* __restrict__ O)
{
  __shared__ unsigned short p_lds[32 * 66];
  const int lane = threadIdx.x;
  const int lr = lane & 15, g = lane >> 4, kl = g * 8;
  const int q0 = blockIdx.x * 32;
  const int bh = blockIdx.y, b = bh >> 4, h = bh & 15;

  const unsigned short* Qp = Qr + (size_t)bh * SQ * HD;
  const unsigned short* Kp = Kt + (size_t)bh * SK * HD;
  const unsigned short* Vp = Vt + (size_t)bh * SK * HD;

  bh8 qf[2][2];
#pragma unroll
  for (int mi = 0; mi < 2; ++mi)
#pragma unroll
    for (int kk = 0; kk < 2; ++kk)
      qf[mi][kk] = *(const bh8*)(Qp + (size_t)(q0 + mi * 16 + lr) * 64 + kk * 32 + kl);

  bh8 ones;
#pragma unroll
  for (int i = 0; i < 8; ++i) ones[i] = (short)0x3F80;

  fx4 oacc[2][4] = {};
  fx4 lacc[2] = {};
  float m[2][4];
#pragma unroll
  for (int mi = 0; mi < 2; ++mi)
#pragma unroll
    for (int j = 0; j < 4; ++j) m[mi][j] = -1e30f;

  for (int t = 0; t < SK / 64; ++t) {
    fx4 sacc[2][4] = {};
#pragma unroll
    for (int kk = 0; kk < 2; ++kk) {
      bh8 kf[4];
#pragma unroll
      for (int ni = 0; ni < 4; ++ni)
        kf[ni] = *(const bh8*)(Kp + (size_t)(t * 4 + ni) * 1024 + kk * 512 + g * 128 + lr * 8);
#pragma unroll
      for (int mi = 0; mi < 2; ++mi)
#pragma unroll
        for (int ni = 0; ni < 4; ++ni)
          sacc[mi][ni] = __builtin_amdgcn_mfma_f32_16x16x32_bf16(qf[mi][kk], kf[ni], sacc[mi][ni], 0, 0, 0);
    }

#pragma unroll
    for (int mi = 0; mi < 2; ++mi)
#pragma unroll
      for (int j = 0; j < 4; ++j) {
        const float s0 = sacc[mi][0][j], s1 = sacc[mi][1][j];
        const float s2 = sacc[mi][2][j], s3 = sacc[mi][3][j];
        float rmax = fmaxf(fmaxf(s0, s1), fmaxf(s2, s3));
        rmax = fmaxf(rmax, __shfl_xor(rmax, 1));
        rmax = fmaxf(rmax, __shfl_xor(rmax, 2));
        rmax = fmaxf(rmax, __shfl_xor(rmax, 4));
        rmax = fmaxf(rmax, __shfl_xor(rmax, 8));
        if (__any(rmax > m[mi][j] + 8.0f)) {   // defer-max (T13)
          const float mnew = fmaxf(m[mi][j], rmax);
          const float al = exp2f(m[mi][j] - mnew);
          m[mi][j] = mnew;
#pragma unroll
          for (int ni = 0; ni < 4; ++ni) oacc[mi][ni][j] *= al;
          lacc[mi][j] *= al;
        }
        sacc[mi][0][j] = exp2f(s0 - m[mi][j]);
        sacc[mi][1][j] = exp2f(s1 - m[mi][j]);
        sacc[mi][2][j] = exp2f(s2 - m[mi][j]);
        sacc[mi][3][j] = exp2f(s3 - m[mi][j]);
      }

    // previous tile's pa reads must complete before overwrite (1-wave block)
    asm volatile("s_waitcnt lgkmcnt(0)" ::: "memory");
    __builtin_amdgcn_sched_barrier(0);
#pragma unroll
    for (int mi = 0; mi < 2; ++mi)
#pragma unroll
      for (int ni = 0; ni < 4; ++ni)
#pragma unroll
        for (int j = 0; j < 4; ++j)
          p_lds[(mi * 16 + 4 * g + j) * 66 + ni * 16 + lr] = f2bf(sacc[mi][ni][j]);
    asm volatile("s_waitcnt lgkmcnt(0)" ::: "memory");
    __builtin_amdgcn_sched_barrier(0);

#pragma unroll
    for (int kk = 0; kk < 2; ++kk) {
      bh8 pa[2], vb[4];
#pragma unroll
      for (int mi = 0; mi < 2; ++mi)
        pa[mi] = *(const bh8*)&p_lds[(mi * 16 + lr) * 66 + kk * 32 + kl];
#pragma unroll
      for (int ni = 0; ni < 4; ++ni)
        vb[ni] = *(const bh8*)(Vp + (size_t)(t * 2 + kk) * 2048 + ni * 512 + g * 128 + lr * 8);
#pragma unroll
      for (int mi = 0; mi < 2; ++mi) {
#pragma unroll
        for (int ni = 0; ni < 4; ++ni)
          oacc[mi][ni] = __builtin_amdgcn_mfma_f32_16x16x32_bf16(pa[mi], vb[ni], oacc[mi][ni], 0, 0, 0);
        lacc[mi] = __builtin_amdgcn_mfma_f32_16x16x32_bf16(pa[mi], ones, lacc[mi], 0, 0, 0);
      }
    }
  }

#pragma unroll
  for (int mi = 0; mi < 2; ++mi)
#pragma unroll
    for (int j = 0; j < 4; ++j) {
      const float inv = 1.0f / lacc[mi][j];
      const int s = q0 + mi * 16 + 4 * g + j;
#pragma unroll
      for (int ni = 0; ni < 4; ++ni) {
        const int d = ni * 16 + lr;
        O[((size_t)(b * SQ + s)) * D_MODEL + h * 64 + d] = f2bf(oacc[mi][ni][j] * inv);
      }
    }
}

extern "C" void kernel_launch(void* const* d_in, const int* in_sizes, int n_in,
                              void* d_out, int out_size, void* d_ws, size_t ws_size,
                              hipStream_t stream) {
  (void)in_sizes; (void)n_in; (void)out_size; (void)ws_size;
  const float* query = (const float*)d_in[0];
  const float* kv    = (const float*)d_in[1];
  const float* q_w   = (const float*)d_in[2];
  const float* q_b   = (const float*)d_in[3];
  const float* k_w   = (const float*)d_in[4];
  const float* k_b   = (const float*)d_in[5];
  const float* v_w   = (const float*)d_in[6];
  const float* v_b   = (const float*)d_in[7];
  const float* out_w = (const float*)d_in[8];
  const float* out_b = (const float*)d_in[9];
  float* out = (float*)d_out;

  unsigned short* ws = (unsigned short*)d_ws;
  unsigned short* qx     = ws;                        // 4Mi shorts
  unsigned short* kvx    = ws + ((size_t)4  << 20);   // 8Mi
  unsigned short* qwx    = ws + ((size_t)12 << 20);   // 1Mi
  unsigned short* kwx    = ws + ((size_t)13 << 20);   // 1Mi
  unsigned short* vwx    = ws + ((size_t)14 << 20);   // 1Mi
  unsigned short* owx    = ws + ((size_t)15 << 20);   // 1Mi
  unsigned short* q_rope = ws + ((size_t)16 << 20);   // 4Mi
  unsigned short* k_t    = ws + ((size_t)20 << 20);   // 8Mi
  unsigned short* v_t    = ws + ((size_t)28 << 20);   // 8Mi
  unsigned short* attn_o = qx;                        // alias: qx dead after Q proj

  hipLaunchKernelGGL(cvt_kernel, dim3(8192), dim3(256), 0, stream,
                     query, kv, q_w, k_w, v_w, out_w, qx, kvx, qwx, kwx, vwx, owx);
  hipLaunchKernelGGL((proj_kernel<0, 2>), dim3(8, 64), dim3(256), 0, stream,
                     qx, qwx, nullptr, q_b, nullptr, q_rope, nullptr, nullptr);
  hipLaunchKernelGGL((proj_kernel<1, 4>), dim3(16, 64), dim3(256), 0, stream,
                     kvx, kwx, vwx, k_b, v_b, k_t, v_t, nullptr);
  hipLaunchKernelGGL(attn_kernel, dim3(32, 64), dim3(64), 0, stream,
                     q_rope, k_t, v_t, attn_o);
  hipLaunchKernelGGL((proj_kernel<2, 2>), dim3(8, 64), dim3(256), 0, stream,
                     attn_o, owx, nullptr, out_b, nullptr, nullptr, nullptr, out);
}

// Round 3
// 212.576 us; speedup vs baseline: 2.9652x; 1.0995x over previous
//
#include <hip/hip_runtime.h>
#include <hip/hip_bf16.h>

#define D_MODEL 1024
#define NHEAD   16
#define HD      64
#define SQ      1024
#define SK      2048

typedef __attribute__((ext_vector_type(8))) short bh8;
typedef __attribute__((ext_vector_type(4))) float fx4;

// scale fold: 1/sqrt(64) * log2(e)
#define QSCALE 0.1803368801111204f

__device__ __forceinline__ unsigned short f2bf(float f) {
  union { float f; unsigned u; } v; v.f = f;
  return (unsigned short)((v.u + 0x7FFFu + ((v.u >> 16) & 1u)) >> 16);
}

#define GLOAD_LDS16(gp, lp)                                                  \
  __builtin_amdgcn_global_load_lds(                                         \
      (const __attribute__((address_space(1))) unsigned int*)(gp),          \
      (__attribute__((address_space(3))) unsigned int*)(lp), 16, 0, 0)

// ---------------- f32 -> bf16 conversion pass ----------------
__global__ __launch_bounds__(256) void cvt_kernel(
    const float* __restrict__ q, const float* __restrict__ kv,
    const float* __restrict__ qw, const float* __restrict__ kw,
    const float* __restrict__ vw, const float* __restrict__ ow,
    unsigned short* __restrict__ qx, unsigned short* __restrict__ kvx,
    unsigned short* __restrict__ qwx, unsigned short* __restrict__ kwx,
    unsigned short* __restrict__ vwx, unsigned short* __restrict__ owx)
{
  const int idx = blockIdx.x * 256 + threadIdx.x;  // vec8 unit, total 2097152
  const float* src; unsigned short* dst; size_t off;
  if (idx < 524288)        { src = q;  dst = qx;  off = idx; }
  else if (idx < 1572864)  { src = kv; dst = kvx; off = idx - 524288; }
  else {
    const int w = idx - 1572864; const int sel = w >> 17; off = w & 131071;
    src = sel == 0 ? qw : sel == 1 ? kw : sel == 2 ? vw : ow;
    dst = sel == 0 ? qwx : sel == 1 ? kwx : sel == 2 ? vwx : owx;
  }
  const float4 a = ((const float4*)src)[off * 2];
  const float4 b = ((const float4*)src)[off * 2 + 1];
  bh8 r;
  r[0] = (short)f2bf(a.x); r[1] = (short)f2bf(a.y);
  r[2] = (short)f2bf(a.z); r[3] = (short)f2bf(a.w);
  r[4] = (short)f2bf(b.x); r[5] = (short)f2bf(b.y);
  r[6] = (short)f2bf(b.z); r[7] = (short)f2bf(b.w);
  *(bh8*)(dst + off * 8) = r;
}

// ---------------- projection GEMMs (m97-style, bf16, LDS-staged) ----------
template <int MODE, int MI>
__global__ __launch_bounds__(256) void proj_kernel(
    const unsigned short* __restrict__ X,
    const unsigned short* __restrict__ W0, const unsigned short* __restrict__ W1,
    const float* __restrict__ b0, const float* __restrict__ b1,
    unsigned short* __restrict__ out0, unsigned short* __restrict__ out1,
    float* __restrict__ outf)
{
  constexpr int BM = MI * 32;
  constexpr int LSH = (MODE == 1) ? 11 : 10;
  __shared__ unsigned short Alds[BM * 32];
  __shared__ unsigned short Blds[128 * 32];

  const int t = threadIdx.x;
  const int lane = t & 63, w = t >> 6;
  const int lr = lane & 15, g = lane >> 4, kl = g * 8;
  const int row0 = blockIdx.y * BM;
  const int colB = blockIdx.x * 128;
  const int wrow = (w >> 1) * (MI * 16);
  const int wcol = (w & 1) * 64;

  const unsigned short* Wsrc = W0;
  const float* bias = b0;
  unsigned short* outp = out0;
  int colW = colB;
  bool isV = false;
  if (MODE == 1 && colB >= 1024) {
    Wsrc = W1; bias = b1; outp = out1; colW = colB - 1024; isV = true;
  }

  const int srow = t >> 2, schunk = (t & 3) * 8;

  fx4 acc[MI][4] = {};
  for (int k0 = 0; k0 < 1024; k0 += 32) {
    __syncthreads();
    GLOAD_LDS16(X + (size_t)(row0 + srow) * 1024 + k0 + schunk, &Alds[t * 8]);
    if (MI == 4)
      GLOAD_LDS16(X + (size_t)(row0 + 64 + srow) * 1024 + k0 + schunk, &Alds[2048 + t * 8]);
    GLOAD_LDS16(Wsrc + (size_t)(colW + srow) * 1024 + k0 + schunk, &Blds[t * 8]);
    GLOAD_LDS16(Wsrc + (size_t)(colW + 64 + srow) * 1024 + k0 + schunk, &Blds[2048 + t * 8]);
    __syncthreads();  // compiler drains vmcnt(0) here

    bh8 af[MI], bf[4];
#pragma unroll
    for (int mi = 0; mi < MI; ++mi)
      af[mi] = *(const bh8*)&Alds[(wrow + mi * 16 + lr) * 32 + kl];
#pragma unroll
    for (int ni = 0; ni < 4; ++ni)
      bf[ni] = *(const bh8*)&Blds[(wcol + ni * 16 + lr) * 32 + kl];
#pragma unroll
    for (int mi = 0; mi < MI; ++mi)
#pragma unroll
      for (int ni = 0; ni < 4; ++ni)
        acc[mi][ni] = __builtin_amdgcn_mfma_f32_16x16x32_bf16(af[mi], bf[ni], acc[mi][ni], 0, 0, 0);
  }

  float bv[4];
#pragma unroll
  for (int ni = 0; ni < 4; ++ni) bv[ni] = bias[colW + wcol + ni * 16 + lr];
#pragma unroll
  for (int mi = 0; mi < MI; ++mi)
#pragma unroll
    for (int ni = 0; ni < 4; ++ni)
#pragma unroll
      for (int j = 0; j < 4; ++j) acc[mi][ni][j] += bv[ni];

  if (MODE == 0 || (MODE == 1 && !isV)) {
    const float c0 = 0.41524101186092029f;  // log2(10000)/32
    const float invf0 = exp2f(-(float)lr * c0);
    const float invf1 = exp2f(-(float)(16 + lr) * c0);
#pragma unroll
    for (int mi = 0; mi < MI; ++mi)
#pragma unroll
      for (int j = 0; j < 4; ++j) {
        const int rg = row0 + wrow + mi * 16 + 4 * g + j;
        const int s = rg & ((MODE == 0) ? 1023 : 2047);
        const float pos = (float)((MODE == 0) ? 2 * s : s);
#pragma unroll
        for (int ni = 0; ni < 2; ++ni) {
          float sn, cs;
          __sincosf(pos * (ni == 0 ? invf0 : invf1), &sn, &cs);
          const float x1 = acc[mi][ni][j], x2 = acc[mi][ni + 2][j];
          acc[mi][ni][j]     = x1 * cs - x2 * sn;
          acc[mi][ni + 2][j] = x2 * cs + x1 * sn;
        }
      }
  }

  const int h = (colW + wcol) >> 6;
#pragma unroll
  for (int mi = 0; mi < MI; ++mi)
#pragma unroll
    for (int j = 0; j < 4; ++j) {
      const int rg = row0 + wrow + mi * 16 + 4 * g + j;
      const int bb = rg >> LSH;
      const int s = rg & ((1 << LSH) - 1);
#pragma unroll
      for (int ni = 0; ni < 4; ++ni) {
        const int d = ni * 16 + lr;
        if (MODE == 0) {
          outp[(((size_t)(bb * 16 + h)) * SQ + s) * 64 + d] = f2bf(acc[mi][ni][j] * QSCALE);
        } else if (MODE == 1) {
          const size_t base = ((size_t)(bb * 16 + h)) * (SK * 64);
          if (!isV) {
            outp[base + (s >> 4) * 1024 + (d >> 5) * 512 + ((d >> 3) & 3) * 128 + (s & 15) * 8 + (d & 7)]
                = f2bf(acc[mi][ni][j]);
          } else {
            outp[base + (s >> 5) * 2048 + (d >> 4) * 512 + ((s >> 3) & 3) * 128 + (d & 15) * 8 + (s & 7)]
                = f2bf(acc[mi][ni][j]);
          }
        } else {
          outf[(size_t)rg * 1024 + colB + wcol + ni * 16 + lr] = acc[mi][ni][j];
        }
      }
    }
}

// ---------------- flash attention: 4 waves/block, K-split x4 --------------
// block = 256 threads; wave w handles K cols [w*512, (w+1)*512) of 32 q rows.
// Exact combine in LDS at the end.
__global__ __launch_bounds__(256, 4) void attn_kernel(
    const unsigned short* __restrict__ Qr, const unsigned short* __restrict__ Kt,
    const unsigned short* __restrict__ Vt, unsigned short* __restrict__ O)
{
  // per-wave P buffer: 32 rows x stride 68 shorts (write-conflict-free);
  // after the loop the same region is reused as f32 partial-O [4][32][68].
  __shared__ __align__(16) char smem[4 * 32 * 68 * 4];
  __shared__ float mlds[4][32];
  __shared__ float llds[4][32];
  __shared__ float gls[32];

  const int lane = threadIdx.x & 63;
  const int w = threadIdx.x >> 6;
  const int lr = lane & 15, g = lane >> 4, kl = g * 8;
  const int q0 = blockIdx.x * 32;
  const int bh = blockIdx.y, b = bh >> 4, h = bh & 15;

  unsigned short* p_lds = (unsigned short*)smem + w * (32 * 68);

  const unsigned short* Qp = Qr + (size_t)bh * SQ * HD;
  const unsigned short* Kp = Kt + (size_t)bh * SK * HD;
  const unsigned short* Vp = Vt + (size_t)bh * SK * HD;

  bh8 qf[2][2];
#pragma unroll
  for (int mi = 0; mi < 2; ++mi)
#pragma unroll
    for (int kk = 0; kk < 2; ++kk)
      qf[mi][kk] = *(const bh8*)(Qp + (size_t)(q0 + mi * 16 + lr) * 64 + kk * 32 + kl);

  bh8 ones;
#pragma unroll
  for (int i = 0; i < 8; ++i) ones[i] = (short)0x3F80;

  fx4 oacc[2][4] = {};
  fx4 lacc[2] = {};
  float m[2][4];
#pragma unroll
  for (int mi = 0; mi < 2; ++mi)
#pragma unroll
    for (int j = 0; j < 4; ++j) m[mi][j] = -1e30f;

  for (int t = 0; t < 8; ++t) {
    fx4 sacc[2][4] = {};
#pragma unroll
    for (int kk = 0; kk < 2; ++kk) {
      bh8 kf[4];
#pragma unroll
      for (int ni = 0; ni < 4; ++ni)
        kf[ni] = *(const bh8*)(Kp + (size_t)(w * 32 + t * 4 + ni) * 1024 + kk * 512 + g * 128 + lr * 8);
#pragma unroll
      for (int mi = 0; mi < 2; ++mi)
#pragma unroll
        for (int ni = 0; ni < 4; ++ni)
          sacc[mi][ni] = __builtin_amdgcn_mfma_f32_16x16x32_bf16(qf[mi][kk], kf[ni], sacc[mi][ni], 0, 0, 0);
    }

#pragma unroll
    for (int mi = 0; mi < 2; ++mi)
#pragma unroll
      for (int j = 0; j < 4; ++j) {
        const float s0 = sacc[mi][0][j], s1 = sacc[mi][1][j];
        const float s2 = sacc[mi][2][j], s3 = sacc[mi][3][j];
        float rmax = fmaxf(fmaxf(s0, s1), fmaxf(s2, s3));
        rmax = fmaxf(rmax, __shfl_xor(rmax, 1));
        rmax = fmaxf(rmax, __shfl_xor(rmax, 2));
        rmax = fmaxf(rmax, __shfl_xor(rmax, 4));
        rmax = fmaxf(rmax, __shfl_xor(rmax, 8));
        if (__any(rmax > m[mi][j] + 8.0f)) {   // defer-max (T13)
          const float mnew = fmaxf(m[mi][j], rmax);
          const float al = exp2f(m[mi][j] - mnew);
          m[mi][j] = mnew;
#pragma unroll
          for (int ni = 0; ni < 4; ++ni) oacc[mi][ni][j] *= al;
          lacc[mi][j] *= al;
        }
        sacc[mi][0][j] = exp2f(s0 - m[mi][j]);
        sacc[mi][1][j] = exp2f(s1 - m[mi][j]);
        sacc[mi][2][j] = exp2f(s2 - m[mi][j]);
        sacc[mi][3][j] = exp2f(s3 - m[mi][j]);
      }

    // previous tile's pa reads must complete before overwrite (per-wave buf)
    asm volatile("s_waitcnt lgkmcnt(0)" ::: "memory");
    __builtin_amdgcn_sched_barrier(0);
#pragma unroll
    for (int mi = 0; mi < 2; ++mi)
#pragma unroll
      for (int ni = 0; ni < 4; ++ni)
#pragma unroll
        for (int j = 0; j < 4; ++j)
          p_lds[(mi * 16 + 4 * g + j) * 68 + ni * 16 + lr] = f2bf(sacc[mi][ni][j]);
    asm volatile("s_waitcnt lgkmcnt(0)" ::: "memory");
    __builtin_amdgcn_sched_barrier(0);

#pragma unroll
    for (int kk = 0; kk < 2; ++kk) {
      bh8 pa[2], vb[4];
#pragma unroll
      for (int mi = 0; mi < 2; ++mi) {
        const unsigned short* pp = &p_lds[(mi * 16 + lr) * 68 + kk * 32 + kl];
        const short4 a = *(const short4*)pp;
        const short4 c = *(const short4*)(pp + 4);
        pa[mi][0] = a.x; pa[mi][1] = a.y; pa[mi][2] = a.z; pa[mi][3] = a.w;
        pa[mi][4] = c.x; pa[mi][5] = c.y; pa[mi][6] = c.z; pa[mi][7] = c.w;
      }
#pragma unroll
      for (int ni = 0; ni < 4; ++ni)
        vb[ni] = *(const bh8*)(Vp + (size_t)(w * 16 + t * 2 + kk) * 2048 + ni * 512 + g * 128 + lr * 8);
#pragma unroll
      for (int mi = 0; mi < 2; ++mi) {
#pragma unroll
        for (int ni = 0; ni < 4; ++ni)
          oacc[mi][ni] = __builtin_amdgcn_mfma_f32_16x16x32_bf16(pa[mi], vb[ni], oacc[mi][ni], 0, 0, 0);
        lacc[mi] = __builtin_amdgcn_mfma_f32_16x16x32_bf16(pa[mi], ones, lacc[mi], 0, 0, 0);
      }
    }
  }

  // ---- combine the 4 K-quarters (exact) ----
  __syncthreads();  // all waves done with p_lds region
  if (lr == 0) {
#pragma unroll
    for (int mi = 0; mi < 2; ++mi)
#pragma unroll
      for (int j = 0; j < 4; ++j) {
        const int row = mi * 16 + 4 * g + j;
        mlds[w][row] = m[mi][j];
        llds[w][row] = lacc[mi][j];
      }
  }
  __syncthreads();

  float* opartw = (float*)smem + w * (32 * 68);
#pragma unroll
  for (int mi = 0; mi < 2; ++mi)
#pragma unroll
    for (int j = 0; j < 4; ++j) {
      const int row = mi * 16 + 4 * g + j;
      const float gm = fmaxf(fmaxf(mlds[0][row], mlds[1][row]),
                             fmaxf(mlds[2][row], mlds[3][row]));
      if (w == 0 && lr == 0) {
        gls[row] = llds[0][row] * exp2f(mlds[0][row] - gm)
                 + llds[1][row] * exp2f(mlds[1][row] - gm)
                 + llds[2][row] * exp2f(mlds[2][row] - gm)
                 + llds[3][row] * exp2f(mlds[3][row] - gm);
      }
      const float sc = exp2f(m[mi][j] - gm);
#pragma unroll
      for (int ni = 0; ni < 4; ++ni)
        opartw[row * 68 + ni * 16 + lr] = oacc[mi][ni][j] * sc;
    }
  __syncthreads();

  const int row = threadIdx.x >> 3;
  const int d0 = (threadIdx.x & 7) * 8;
  float a8[8] = {};
#pragma unroll
  for (int ww = 0; ww < 4; ++ww) {
    const float* pp = (const float*)smem + ww * (32 * 68) + row * 68 + d0;
    const float4 x = *(const float4*)pp;
    const float4 y = *(const float4*)(pp + 4);
    a8[0] += x.x; a8[1] += x.y; a8[2] += x.z; a8[3] += x.w;
    a8[4] += y.x; a8[5] += y.y; a8[6] += y.z; a8[7] += y.w;
  }
  const float inv = 1.0f / gls[row];
  bh8 r;
#pragma unroll
  for (int i = 0; i < 8; ++i) r[i] = (short)f2bf(a8[i] * inv);
  *(bh8*)&O[((size_t)(b * SQ + q0 + row)) * D_MODEL + h * 64 + d0] = r;
}

extern "C" void kernel_launch(void* const* d_in, const int* in_sizes, int n_in,
                              void* d_out, int out_size, void* d_ws, size_t ws_size,
                              hipStream_t stream) {
  (void)in_sizes; (void)n_in; (void)out_size; (void)ws_size;
  const float* query = (const float*)d_in[0];
  const float* kv    = (const float*)d_in[1];
  const float* q_w   = (const float*)d_in[2];
  const float* q_b   = (const float*)d_in[3];
  const float* k_w   = (const float*)d_in[4];
  const float* k_b   = (const float*)d_in[5];
  const float* v_w   = (const float*)d_in[6];
  const float* v_b   = (const float*)d_in[7];
  const float* out_w = (const float*)d_in[8];
  const float* out_b = (const float*)d_in[9];
  float* out = (float*)d_out;

  unsigned short* ws = (unsigned short*)d_ws;
  unsigned short* qx     = ws;                        // 4Mi shorts
  unsigned short* kvx    = ws + ((size_t)4  << 20);   // 8Mi
  unsigned short* qwx    = ws + ((size_t)12 << 20);   // 1Mi
  unsigned short* kwx    = ws + ((size_t)13 << 20);   // 1Mi
  unsigned short* vwx    = ws + ((size_t)14 << 20);   // 1Mi
  unsigned short* owx    = ws + ((size_t)15 << 20);   // 1Mi
  unsigned short* q_rope = ws + ((size_t)16 << 20);   // 4Mi
  unsigned short* k_t    = ws + ((size_t)20 << 20);   // 8Mi
  unsigned short* v_t    = ws + ((size_t)28 << 20);   // 8Mi
  unsigned short* attn_o = qx;                        // alias: qx dead after Q proj

  hipLaunchKernelGGL(cvt_kernel, dim3(8192), dim3(256), 0, stream,
                     query, kv, q_w, k_w, v_w, out_w, qx, kvx, qwx, kwx, vwx, owx);
  hipLaunchKernelGGL((proj_kernel<0, 2>), dim3(8, 64), dim3(256), 0, stream,
                     qx, qwx, nullptr, q_b, nullptr, q_rope, nullptr, nullptr);
  hipLaunchKernelGGL((proj_kernel<1, 4>), dim3(16, 64), dim3(256), 0, stream,
                     kvx, kwx, vwx, k_b, v_b, k_t, v_t, nullptr);
  hipLaunchKernelGGL(attn_kernel, dim3(32, 64), dim3(256), 0, stream,
                     q_rope, k_t, v_t, attn_o);
  hipLaunchKernelGGL((proj_kernel<2, 2>), dim3(8, 64), dim3(256), 0, stream,
                     attn_o, owx, nullptr, out_b, nullptr, nullptr, nullptr, out);
}